// Round 17
// baseline (250.285 us; speedup 1.0000x reference)
//
#include <hip/hip_runtime.h>
#include <cstdint>

typedef __bf16 bf16;
typedef __bf16 bf16x8 __attribute__((ext_vector_type(8)));
typedef __bf16 bf16x4 __attribute__((ext_vector_type(4)));
typedef float  f32x4  __attribute__((ext_vector_type(4)));

#define HIDDEN 2304
#define NQ 2048
#define NKV 1024
#define SEQ 2048

typedef __attribute__((address_space(1))) void gv_t;
typedef __attribute__((address_space(3))) void lv_t;
__device__ __forceinline__ void gld16(const void* g, void* l) {
  __builtin_amdgcn_global_load_lds((gv_t*)g, (lv_t*)l, 16, 0, 0);
}

#define BAR()    asm volatile("s_barrier" ::: "memory")
#define LGKM(n)  asm volatile("s_waitcnt lgkmcnt(" #n ")" ::: "memory")
#define VM8()    asm volatile("s_waitcnt vmcnt(8)" ::: "memory")
#define VM6()    asm volatile("s_waitcnt vmcnt(6)" ::: "memory")
#define VM2()    asm volatile("s_waitcnt vmcnt(2)" ::: "memory")
#define VM0()    asm volatile("s_waitcnt vmcnt(0)" ::: "memory")
#define SCHED0() __builtin_amdgcn_sched_barrier(0)

// ---------------- RMSNorm + bf16 cast ----------------
__global__ __launch_bounds__(256) void rmsnorm_kernel(const float* __restrict__ x,
                                                      const float* __restrict__ w,
                                                      bf16* __restrict__ xb) {
  const int row = blockIdx.x, t = threadIdx.x;
  const float* xr = x + (size_t)row * HIDDEN;
  float v[9]; float ss = 0.f;
#pragma unroll
  for (int i = 0; i < 9; ++i) { v[i] = xr[t + i * 256]; ss += v[i] * v[i]; }
#pragma unroll
  for (int o = 32; o; o >>= 1) ss += __shfl_xor(ss, o, 64);
  __shared__ float wss[4];
  if ((t & 63) == 0) wss[t >> 6] = ss;
  __syncthreads();
  ss = wss[0] + wss[1] + wss[2] + wss[3];
  const float rs = rsqrtf(ss * (1.0f / HIDDEN) + 1e-6f);
  bf16* xo = xb + (size_t)row * HIDDEN;
#pragma unroll
  for (int i = 0; i < 9; ++i) xo[t + i * 256] = (bf16)(v[i] * rs * (1.0f + w[t + i * 256]));
}

// ---------------- fused f32 -> bf16 weight convert ----------
// Wq, Wk rows PERMUTED for fused RoPE with SAME-LANE pairing:
// head-dim d -> col(d) = ((d>>4)&7)<<5 | (d>>7)<<4 | (d&15).
#define NW0 (2048 * 2304)
#define NW1 (1024 * 2304)
#define NW3 (2304 * 2048)
__global__ __launch_bounds__(256) void cvt4_kernel(const float* __restrict__ s0, const float* __restrict__ s1,
                                                   const float* __restrict__ s2, const float* __restrict__ s3,
                                                   bf16* __restrict__ d0, bf16* __restrict__ d1,
                                                   bf16* __restrict__ d2, bf16* __restrict__ d3) {
  int i = (blockIdx.x * 256 + threadIdx.x) * 4;
  const float* s; bf16* dst; size_t oidx;
  if (i < NW0) {
    s = s0; const int r = i / 2304, c = i % 2304, d = r & 255;
    const int col = (((d >> 4) & 7) << 5) | ((d >> 7) << 4) | (d & 15);
    oidx = (size_t)((r & ~255) | col) * 2304 + c; dst = d0;
  } else if (i < NW0 + NW1) {
    i -= NW0;
    s = s1; const int r = i / 2304, c = i % 2304, d = r & 255;
    const int col = (((d >> 4) & 7) << 5) | ((d >> 7) << 4) | (d & 15);
    oidx = (size_t)((r & ~255) | col) * 2304 + c; dst = d1;
  } else if (i < NW0 + 2 * NW1) {
    i -= NW0 + NW1; s = s2; oidx = i; dst = d2;
  } else {
    i -= NW0 + 2 * NW1; s = s3; oidx = i; dst = d3;
  }
  const float4 f = *(const float4*)(s + i);
  bf16x4 o; o.x = (bf16)f.x; o.y = (bf16)f.y; o.z = (bf16)f.z; o.w = (bf16)f.w;
  *(bf16x4*)(dst + oidx) = o;
}

// ======== 256x256 8-phase GEMM (r8 engine) with fused-RoPE epilogue ========
__device__ __forceinline__ void stage_half(const char* gbase, int stride, char* ldshalf, int tid) {
  const int c2 = ((tid & 7) * 16) ^ (((tid >> 3) & 7) << 4);  // pre-swizzled global col
#pragma unroll
  for (int q = 0; q < 2; ++q) {
    const int r = q * 64 + (tid >> 3);
    gld16(gbase + (size_t)r * stride + c2, ldshalf + q * 8192 + tid * 16);
  }
}

template<int MH, int NH, int KS>
__device__ __forceinline__ void mfma_burst(const bf16x8 (&af)[4][2], const bf16x8 (&bn)[2][2],
                                           f32x4 (&acc)[8][4]) {
  __builtin_amdgcn_s_setprio(1);
#pragma unroll
  for (int m = 0; m < 4; ++m)
#pragma unroll
    for (int n = 0; n < 2; ++n)
      acc[MH * 4 + m][NH * 2 + n] =
          __builtin_amdgcn_mfma_f32_16x16x32_bf16(af[m][KS], bn[n][KS], acc[MH * 4 + m][NH * 2 + n], 0, 0, 0);
  __builtin_amdgcn_s_setprio(0);
}

template<int NT, int NY, int MODE>
__global__ __launch_bounds__(512) void gemm8p(const bf16* __restrict__ A, const bf16* __restrict__ B,
                                              bf16* __restrict__ Cq, bf16* __restrict__ Ck,
                                              bf16* __restrict__ Cvt, float* __restrict__ fo,
                                              const float* __restrict__ resid, int Nd,
                                              const float* __restrict__ cosb,
                                              const float* __restrict__ sinb) {
  __shared__ char lds[131072];
  const int Ks = NT * 128;
  const char* Aby = (const char*)A;
  const char* Bby = (const char*)B;

  int wg = blockIdx.x;
  const int chunk = (int)gridDim.x >> 3;
  wg = (wg & 7) * chunk + (wg >> 3);
  const int by = wg % NY, bx = wg / NY;
  const int m0 = bx * 256, n0 = by * 256;

  const int tid = threadIdx.x, lane = tid & 63, wv = tid >> 6;
  const int wm = wv >> 2, wn = wv & 3;
  const int r16 = lane & 15, g = lane >> 4;
  const int xr = (r16 & 7) << 4;
  const int cb0 = (g * 16) ^ xr, cb1 = (64 + g * 16) ^ xr;
  const int rdA = wm * 16384 + r16 * 128;
  const int rdB = 32768 + (wn >> 1) * 16384 + (wn & 1) * 8192 + r16 * 128;

  const char* A0g = Aby + (size_t)m0 * Ks;
  const char* A1g = Aby + (size_t)(m0 + 128) * Ks;
  const char* B0g = Bby + (size_t)n0 * Ks;
  const char* B1g = Bby + (size_t)(n0 + 128) * Ks;

  f32x4 acc[8][4] = {};
  bf16x8 a0[4][2], a1[4][2], bb01[2][2], bb23[2][2];

  auto read_a0bb01 = [&](const char* buf) {
#pragma unroll
    for (int n = 0; n < 2; ++n) bb01[n][0] = *(const bf16x8*)(buf + rdB + n * 2048 + cb0);
#pragma unroll
    for (int n = 0; n < 2; ++n) bb01[n][1] = *(const bf16x8*)(buf + rdB + n * 2048 + cb1);
#pragma unroll
    for (int m = 0; m < 4; ++m) a0[m][0] = *(const bf16x8*)(buf + rdA + m * 2048 + cb0);
#pragma unroll
    for (int m = 0; m < 4; ++m) a0[m][1] = *(const bf16x8*)(buf + rdA + m * 2048 + cb1);
  };

  stage_half(A0g, Ks, lds + 0,     tid);
  stage_half(A1g, Ks, lds + 16384, tid);
  stage_half(B0g, Ks, lds + 32768, tid);
  stage_half(B1g, Ks, lds + 49152, tid);
  stage_half(B0g + 128, Ks, lds + 65536 + 32768, tid);
  stage_half(A0g + 128, Ks, lds + 65536 + 0,     tid);
  stage_half(A1g + 128, Ks, lds + 65536 + 16384, tid);
  VM6(); BAR();
  read_a0bb01(lds);

  for (int t = 0; t < NT; ++t) {
    const char* bufc = lds + (size_t)(t & 1) * 65536;
    char* bufn = lds + (size_t)((t + 1) & 1) * 65536;
    char* bufs = lds + (size_t)(t & 1) * 65536;
    LGKM(0);
#pragma unroll
    for (int n = 0; n < 2; ++n) bb23[n][0] = *(const bf16x8*)(bufc + rdB + (2 + n) * 2048 + cb0);
#pragma unroll
    for (int n = 0; n < 2; ++n) bb23[n][1] = *(const bf16x8*)(bufc + rdB + (2 + n) * 2048 + cb1);
#pragma unroll
    for (int m = 0; m < 4; ++m) a1[m][0] = *(const bf16x8*)(bufc + rdA + 8192 + m * 2048 + cb0);
#pragma unroll
    for (int m = 0; m < 4; ++m) a1[m][1] = *(const bf16x8*)(bufc + rdA + 8192 + m * 2048 + cb1);
    SCHED0();
    mfma_burst<0, 0, 0>(a0, bb01, acc);
    mfma_burst<0, 0, 1>(a0, bb01, acc);
    SCHED0(); BAR();
    LGKM(8);
    if (t + 1 < NT)
      stage_half(B1g + (size_t)(t + 1) * 128, Ks, bufn + 49152, tid);
    SCHED0();
    mfma_burst<0, 1, 0>(a0, bb23, acc);
    mfma_burst<0, 1, 1>(a0, bb23, acc);
    SCHED0(); BAR();
    LGKM(0);
    if (t + 2 < NT)
      stage_half(B0g + (size_t)(t + 2) * 128, Ks, bufs + 32768, tid);
    SCHED0();
    mfma_burst<1, 0, 0>(a1, bb01, acc);
    mfma_burst<1, 0, 1>(a1, bb01, acc);
    SCHED0(); BAR();
    if (t < NT - 2) { VM2(); } else if (t == NT - 2) { VM0(); }
    if (t + 2 < NT) {
      stage_half(A0g + (size_t)(t + 2) * 128, Ks, bufs + 0,     tid);
      stage_half(A1g + (size_t)(t + 2) * 128, Ks, bufs + 16384, tid);
    }
    SCHED0();
    mfma_burst<1, 1, 0>(a1, bb23, acc);
    mfma_burst<1, 1, 1>(a1, bb23, acc);
    SCHED0(); BAR();
    if (t + 1 < NT) read_a0bb01(bufn);
  }

  const int mrow = m0 + wm * 128 + g * 4;
  if constexpr (MODE == 0) {
    if (n0 < 3072) {
      const bool isQ = (n0 < 2048);
      bf16* Cb = isQ ? (Cq + n0) : (Ck + (n0 - 2048));
      const int ld = isQ ? 2048 : 1024;
#pragma unroll
      for (int i = 0; i < 8; ++i)
#pragma unroll
        for (int jp = 0; jp < 2; ++jp) {
          const int col = wn * 64 + jp * 32 + r16;
          const int de = (col & 15) | (((col >> 5) & 7) << 4);
#pragma unroll
          for (int e = 0; e < 4; ++e) {
            const int m = mrow + i * 16 + e;
            const float c  = cosb[(size_t)m * 256 + de];
            const float sn = sinb[(size_t)m * 256 + de];
            const float v0 = acc[i][jp * 2][e];
            const float v1 = acc[i][jp * 2 + 1][e];
            Cb[(size_t)m * ld + de]       = (bf16)(v0 * c - v1 * sn);
            Cb[(size_t)m * ld + de + 128] = (bf16)(v1 * c + v0 * sn);
          }
        }
    } else {
      const int ncol = n0 + wn * 64 + r16;
#pragma unroll
      for (int i = 0; i < 8; ++i)
#pragma unroll
        for (int j = 0; j < 4; ++j)
#pragma unroll
          for (int e = 0; e < 4; ++e) {
            const int m = mrow + i * 16 + e;
            const int n = ncol + j * 16;
            const int b2 = m >> 11, s = m & 2047;
            Cvt[((size_t)b2 * 1024 + (n - 3072)) * SEQ + s] = (bf16)acc[i][j][e];
          }
    }
  } else {
    const int ncol = n0 + wn * 64 + r16;
#pragma unroll
    for (int i = 0; i < 8; ++i)
#pragma unroll
      for (int j = 0; j < 4; ++j)
#pragma unroll
        for (int e = 0; e < 4; ++e) {
          const int m = mrow + i * 16 + e;
          const int n = ncol + j * 16;
          fo[(size_t)m * Nd + n] = acc[i][j][e] + resid[(size_t)m * Nd + n];
        }
  }
}

// ======== Flash attention v2: 4 waves = 2 q-groups(32 rows) x 2 roles ========
// KT=64. Wave (wq,wd): QK for keys [wd*32,+32) (P -> shared LDS); PV for
// d in [wd*128,+128) over ALL 64 keys (no oacc merge; only lrun merges).
// K/V/Q staged via global_load_lds, single-buffered, counted vmcnt(8):
// K(t+1) issued post-QK-barrier (arrives under softmax+PV), V(t+1) issued
// post-PV-barrier (arrives under next QK). Packed LDS + both-sides XOR
// swizzle (pre-swizzled global source, same XOR on reads; 2-way max = free).
__device__ __forceinline__ void stage_k64(const char* kgb, int j0, char* ksl, int t) {
#pragma unroll
  for (int p = 0; p < 8; ++p) {
    const int o = p * 4096 + t * 16;
    const int row = o >> 9, cb = o & 511;
    gld16(kgb + (size_t)(j0 + row) * 2048 + (cb ^ ((row & 7) << 4)), ksl + o);
  }
}
__device__ __forceinline__ void stage_v64(const char* vgb, int j0, char* vtl, int t) {
#pragma unroll
  for (int p = 0; p < 8; ++p) {
    const int o = p * 4096 + t * 16;
    const int row = o >> 7, cb = o & 127;
    gld16(vgb + (size_t)row * 4096 + j0 * 2 + (cb ^ ((row & 7) << 4)), vtl + o);
  }
}
__device__ __forceinline__ void stage_q64(const char* qgb, char* qs, int t) {
#pragma unroll
  for (int p = 0; p < 8; ++p) {
    const int o = p * 4096 + t * 16;
    const int row = o >> 9, cb = o & 511;
    gld16(qgb + (size_t)row * 4096 + (cb ^ ((row & 7) << 4)), qs + o);
  }
}

__global__ __launch_bounds__(256) void attn_kernel(const bf16* __restrict__ q, const bf16* __restrict__ k,
                                                   const bf16* __restrict__ vt, bf16* __restrict__ ao) {
  __shared__ char smem[75264];
  char* const ksl = smem;                      // K tile packed [64][512B] (Q tile in prologue)
  char* const vtl = smem + 32768;              // V^T tile packed [256][128B]
  bf16* const pl  = (bf16*)(smem + 65536);     // P [64 rows][72]
  float* const lbuf = (float*)(smem + 74752);  // lrun exchange [4 waves][32]
  int qt = blockIdx.x;
  const int h = blockIdx.y, b = blockIdx.z;
  if (b) qt = 31 - qt;                         // heavy+light pairing
  const int kvh = h >> 1;
  const int t = threadIdx.x, lane = t & 63, w = t >> 6;
  const int wq = w >> 1, wd = w & 1;
  const int r16 = lane & 15, g = lane >> 4;
  const int xr = (r16 & 7) << 4;
  const int i_base = qt * 64;
  const int R0 = i_base + wq * 32;

  const char* qgb = (const char*)(q + ((size_t)(b * SEQ + i_base)) * NQ + h * 256);
  const char* kgb = (const char*)(k + (size_t)b * SEQ * NKV + kvh * 256);
  const char* vgb = (const char*)(vt + ((size_t)b * NKV + kvh * 256) * SEQ);

  // prologue: Q -> ksl region, hoist aq, then K/V tile 0
  stage_q64(qgb, ksl, t);
  VM0(); BAR();
  bf16x8 aq[2][8];
#pragma unroll
  for (int rg = 0; rg < 2; ++rg)
#pragma unroll
    for (int c = 0; c < 8; ++c)
      aq[rg][c] = *(const bf16x8*)(ksl + (wq * 32 + rg * 16 + r16) * 512 + ((c * 64 + g * 16) ^ xr));
  LGKM(0); BAR();

  int jb = i_base - 1023; if (jb < 0) jb = 0; jb &= ~63;
  const int je = i_base + 63;
  stage_k64(kgb, jb, ksl, t);
  stage_v64(vgb, jb, vtl, t);

  f32x4 oacc[2][8] = {};
  float lrun[2][4] = {};

  for (int j0 = jb; j0 <= je; j0 += 64) {
    const bool haveNext = (j0 + 64 <= je);
    VM8(); BAR();  // K(t) landed everywhere (V(t) still in flight)
    // ---- QK: this wave's 32 keys x its 32 q-rows ----
    f32x4 sc[2][2] = {};
#pragma unroll
    for (int c = 0; c < 8; ++c) {
      const int cb = (c * 64 + g * 16) ^ xr;
      const bf16x8 b0 = *(const bf16x8*)(ksl + (wd * 32 + r16) * 512 + cb);
      const bf16x8 b1 = *(const bf16x8*)(ksl + (wd * 32 + 16 + r16) * 512 + cb);
      sc[0][0] = __builtin_amdgcn_mfma_f32_16x16x32_bf16(aq[0][c], b0, sc[0][0], 0, 0, 0);
      sc[0][1] = __builtin_amdgcn_mfma_f32_16x16x32_bf16(aq[0][c], b1, sc[0][1], 0, 0, 0);
      sc[1][0] = __builtin_amdgcn_mfma_f32_16x16x32_bf16(aq[1][c], b0, sc[1][0], 0, 0, 0);
      sc[1][1] = __builtin_amdgcn_mfma_f32_16x16x32_bf16(aq[1][c], b1, sc[1][1], 0, 0, 0);
    }
    LGKM(0); BAR();  // all waves' K reads complete
    if (haveNext) stage_k64(kgb, j0 + 64, ksl, t);
    // ---- softmax (fixed shift 50; see r2 derivation) ----
    const int J0 = j0 + wd * 32;
    const bool full = (J0 + 31 <= R0) && (R0 - J0 <= 992);
#pragma unroll
    for (int rg = 0; rg < 2; ++rg)
#pragma unroll
      for (int e = 0; e < 4; ++e) {
        const float t0 = __expf(sc[rg][0][e] * 0.0025f);
        const float t1 = __expf(sc[rg][1][e] * 0.0025f);
        float p0 = __expf(-100.0f / (t0 + 1.0f));
        float p1 = __expf(-100.0f / (t1 + 1.0f));
        if (!full) {
          const int irow = R0 + rg * 16 + g * 4 + e;
          const int jg0 = J0 + r16, jg1 = J0 + 16 + r16;
          if (jg0 > irow || irow - jg0 >= 1024) p0 = 0.f;
          if (jg1 > irow || irow - jg1 >= 1024) p1 = 0.f;
        }
        const bf16 pb0 = (bf16)p0, pb1 = (bf16)p1;
        lrun[rg][e] += (float)pb0 + (float)pb1;
        const int prow = wq * 32 + rg * 16 + g * 4 + e;
        pl[prow * 72 + wd * 32 + r16] = pb0;
        pl[prow * 72 + wd * 32 + 16 + r16] = pb1;
      }
    LGKM(0);
    if (haveNext) { VM8(); } else { VM0(); }  // V(t) landed (K(t+1) may fly)
    BAR();                                    // + pl visible to sibling
    // ---- PV: all 64 keys x this wave's d-half ----
#pragma unroll
    for (int ks = 0; ks < 2; ++ks) {
      const bf16x8 pa0 = *(const bf16x8*)(pl + (wq * 32 + r16) * 72 + ks * 32 + g * 8);
      const bf16x8 pa1 = *(const bf16x8*)(pl + (wq * 32 + 16 + r16) * 72 + ks * 32 + g * 8);
#pragma unroll
      for (int nf = 0; nf < 8; ++nf) {
        const bf16x8 vb = *(const bf16x8*)(vtl + (wd * 128 + nf * 16 + r16) * 128 + ((ks * 64 + g * 16) ^ xr));
        oacc[0][nf] = __builtin_amdgcn_mfma_f32_16x16x32_bf16(pa0, vb, oacc[0][nf], 0, 0, 0);
        oacc[1][nf] = __builtin_amdgcn_mfma_f32_16x16x32_bf16(pa1, vb, oacc[1][nf], 0, 0, 0);
      }
    }
    LGKM(0); BAR();  // all waves' V + pl reads complete
    if (haveNext) stage_v64(vgb, j0 + 64, vtl, t);
  }

  // ---- lrun reduce over r16 lanes, then cross-wd merge via LDS ----
#pragma unroll
  for (int rg = 0; rg < 2; ++rg)
#pragma unroll
    for (int e = 0; e < 4; ++e) {
#pragma unroll
      for (int o = 1; o < 16; o <<= 1) lrun[rg][e] += __shfl_xor(lrun[rg][e], o, 64);
      if (r16 == 0) lbuf[w * 32 + rg * 16 + g * 4 + e] = lrun[rg][e];
    }
  LGKM(0); BAR();
  float inv[2][4];
#pragma unroll
  for (int rg = 0; rg < 2; ++rg)
#pragma unroll
    for (int e = 0; e < 4; ++e)
      inv[rg][e] = 1.0f / (lrun[rg][e] + lbuf[(w ^ 1) * 32 + rg * 16 + g * 4 + e]);

  bf16* aor = ao + ((size_t)(b * SEQ + R0)) * NQ + h * 256 + wd * 128;
#pragma unroll
  for (int rg = 0; rg < 2; ++rg)
#pragma unroll
    for (int nf = 0; nf < 8; ++nf)
#pragma unroll
      for (int e = 0; e < 4; ++e)
        aor[(size_t)(rg * 16 + g * 4 + e) * NQ + nf * 16 + r16] = (bf16)(oacc[rg][nf][e] * inv[rg][e]);
}

extern "C" void kernel_launch(void* const* d_in, const int* in_sizes, int n_in,
                              void* d_out, int out_size, void* d_ws, size_t ws_size,
                              hipStream_t stream) {
  const float* hs   = (const float*)d_in[0];
  const float* cosb = (const float*)d_in[1];
  const float* sinb = (const float*)d_in[2];
  const float* rw   = (const float*)d_in[3];
  const float* Wq   = (const float*)d_in[4];
  const float* Wk   = (const float*)d_in[5];
  const float* Wv   = (const float*)d_in[6];
  const float* Wo   = (const float*)d_in[7];
  float* out = (float*)d_out;
  char* ws = (char*)d_ws;

  bf16* xb   = (bf16*)(ws);             // 4096x2304
  bf16* wqkv = (bf16*)(ws + 18874368);  // [4096][2304]: Wq(2048) | Wk(1024) | Wv(1024)
  bf16* wkb  = wqkv + (size_t)2048 * 2304;
  bf16* wvb  = wqkv + (size_t)3072 * 2304;
  bf16* wob  = (bf16*)(ws + 37748736);  // 2304x2048
  bf16* qg   = (bf16*)(ws + 47185920);  // 4096x2048
  bf16* kg   = (bf16*)(ws + 63963136);  // 4096x1024
  bf16* vtg  = (bf16*)(ws + 72351744);  // [2][1024][2048]
  bf16* ag   = (bf16*)(ws + 80740352);  // 4096x2048

  rmsnorm_kernel<<<4096, 256, 0, stream>>>(hs, rw, xb);
  cvt4_kernel<<<(NW0 + 2 * NW1 + NW3) / 4 / 256, 256, 0, stream>>>(Wq, Wk, Wv, Wo, wqkv, wkb, wvb, wob);
  // QKV: M=4096, N=4096, K=2304 (NT=36), grid 16x16=256, fused RoPE epilogue
  gemm8p<36, 16, 0><<<256, 512, 0, stream>>>(xb, wqkv, qg, kg, vtg, nullptr, nullptr, 4096, cosb, sinb);
  attn_kernel<<<dim3(32, 8, 2), 256, 0, stream>>>(qg, kg, vtg, ag);
  // O-proj: M=4096, N=2304, K=2048 (NT=32), grid 16x9=144, direct f32+resid
  gemm8p<32, 9, 1><<<144, 512, 0, stream>>>(ag, wob, nullptr, nullptr, nullptr, out, hs, 2304, nullptr, nullptr);
}

// Round 18
// 224.342 us; speedup vs baseline: 1.1156x; 1.1156x over previous
//
#include <hip/hip_runtime.h>
#include <cstdint>

typedef __bf16 bf16;
typedef __bf16 bf16x8 __attribute__((ext_vector_type(8)));
typedef __bf16 bf16x4 __attribute__((ext_vector_type(4)));
typedef float  f32x4  __attribute__((ext_vector_type(4)));

#define HIDDEN 2304
#define NQ 2048
#define NKV 1024
#define SEQ 2048

typedef __attribute__((address_space(1))) void gv_t;
typedef __attribute__((address_space(3))) void lv_t;
__device__ __forceinline__ void gld16(const void* g, void* l) {
  __builtin_amdgcn_global_load_lds((gv_t*)g, (lv_t*)l, 16, 0, 0);
}

#define BAR()    asm volatile("s_barrier" ::: "memory")
#define LGKM(n)  asm volatile("s_waitcnt lgkmcnt(" #n ")" ::: "memory")
#define VM6()    asm volatile("s_waitcnt vmcnt(6)" ::: "memory")
#define VM2()    asm volatile("s_waitcnt vmcnt(2)" ::: "memory")
#define VM0()    asm volatile("s_waitcnt vmcnt(0)" ::: "memory")
#define SCHED0() __builtin_amdgcn_sched_barrier(0)

// ---------------- RMSNorm + bf16 cast ----------------
__global__ __launch_bounds__(256) void rmsnorm_kernel(const float* __restrict__ x,
                                                      const float* __restrict__ w,
                                                      bf16* __restrict__ xb) {
  const int row = blockIdx.x, t = threadIdx.x;
  const float* xr = x + (size_t)row * HIDDEN;
  float v[9]; float ss = 0.f;
#pragma unroll
  for (int i = 0; i < 9; ++i) { v[i] = xr[t + i * 256]; ss += v[i] * v[i]; }
#pragma unroll
  for (int o = 32; o; o >>= 1) ss += __shfl_xor(ss, o, 64);
  __shared__ float wss[4];
  if ((t & 63) == 0) wss[t >> 6] = ss;
  __syncthreads();
  ss = wss[0] + wss[1] + wss[2] + wss[3];
  const float rs = rsqrtf(ss * (1.0f / HIDDEN) + 1e-6f);
  bf16* xo = xb + (size_t)row * HIDDEN;
#pragma unroll
  for (int i = 0; i < 9; ++i) xo[t + i * 256] = (bf16)(v[i] * rs * (1.0f + w[t + i * 256]));
}

// ---------------- fused f32 -> bf16 weight convert ----------
// Wq, Wk rows PERMUTED for fused RoPE with SAME-LANE pairing:
// head-dim d -> col(d) = ((d>>4)&7)<<5 | (d>>7)<<4 | (d&15).
#define NW0 (2048 * 2304)
#define NW1 (1024 * 2304)
#define NW3 (2304 * 2048)
__global__ __launch_bounds__(256) void cvt4_kernel(const float* __restrict__ s0, const float* __restrict__ s1,
                                                   const float* __restrict__ s2, const float* __restrict__ s3,
                                                   bf16* __restrict__ d0, bf16* __restrict__ d1,
                                                   bf16* __restrict__ d2, bf16* __restrict__ d3) {
  int i = (blockIdx.x * 256 + threadIdx.x) * 4;
  const float* s; bf16* dst; size_t oidx;
  if (i < NW0) {
    s = s0; const int r = i / 2304, c = i % 2304, d = r & 255;
    const int col = (((d >> 4) & 7) << 5) | ((d >> 7) << 4) | (d & 15);
    oidx = (size_t)((r & ~255) | col) * 2304 + c; dst = d0;
  } else if (i < NW0 + NW1) {
    i -= NW0;
    s = s1; const int r = i / 2304, c = i % 2304, d = r & 255;
    const int col = (((d >> 4) & 7) << 5) | ((d >> 7) << 4) | (d & 15);
    oidx = (size_t)((r & ~255) | col) * 2304 + c; dst = d1;
  } else if (i < NW0 + 2 * NW1) {
    i -= NW0 + NW1; s = s2; oidx = i; dst = d2;
  } else {
    i -= NW0 + 2 * NW1; s = s3; oidx = i; dst = d3;
  }
  const float4 f = *(const float4*)(s + i);
  bf16x4 o; o.x = (bf16)f.x; o.y = (bf16)f.y; o.z = (bf16)f.z; o.w = (bf16)f.w;
  *(bf16x4*)(dst + oidx) = o;
}

// ======== 256x256 8-phase GEMM (r8 engine) with fused-RoPE epilogue ========
__device__ __forceinline__ void stage_half(const char* gbase, int stride, char* ldshalf, int tid) {
  const int c2 = ((tid & 7) * 16) ^ (((tid >> 3) & 7) << 4);  // pre-swizzled global col
#pragma unroll
  for (int q = 0; q < 2; ++q) {
    const int r = q * 64 + (tid >> 3);
    gld16(gbase + (size_t)r * stride + c2, ldshalf + q * 8192 + tid * 16);
  }
}

template<int MH, int NH, int KS>
__device__ __forceinline__ void mfma_burst(const bf16x8 (&af)[4][2], const bf16x8 (&bn)[2][2],
                                           f32x4 (&acc)[8][4]) {
  __builtin_amdgcn_s_setprio(1);
#pragma unroll
  for (int m = 0; m < 4; ++m)
#pragma unroll
    for (int n = 0; n < 2; ++n)
      acc[MH * 4 + m][NH * 2 + n] =
          __builtin_amdgcn_mfma_f32_16x16x32_bf16(af[m][KS], bn[n][KS], acc[MH * 4 + m][NH * 2 + n], 0, 0, 0);
  __builtin_amdgcn_s_setprio(0);
}

// MODE 0: fused QKV epilogue. N=4096 tiles: n0<2048 Q (RoPE, same-lane pair),
//         n0 in [2048,3072) K (RoPE), n0>=3072 V^T.
// MODE 1: f32 out = acc + residual (direct store).
template<int NT, int NY, int MODE>
__global__ __launch_bounds__(512) void gemm8p(const bf16* __restrict__ A, const bf16* __restrict__ B,
                                              bf16* __restrict__ Cq, bf16* __restrict__ Ck,
                                              bf16* __restrict__ Cvt, float* __restrict__ fo,
                                              const float* __restrict__ resid, int Nd,
                                              const float* __restrict__ cosb,
                                              const float* __restrict__ sinb) {
  __shared__ char lds[131072];
  const int Ks = NT * 128;  // row stride in BYTES
  const char* Aby = (const char*)A;
  const char* Bby = (const char*)B;

  int wg = blockIdx.x;
  const int chunk = (int)gridDim.x >> 3;
  wg = (wg & 7) * chunk + (wg >> 3);              // XCD-bijective swizzle (grid%8==0)
  const int by = wg % NY, bx = wg / NY;
  const int m0 = bx * 256, n0 = by * 256;

  const int tid = threadIdx.x, lane = tid & 63, wv = tid >> 6;
  const int wm = wv >> 2, wn = wv & 3;
  const int r16 = lane & 15, g = lane >> 4;
  const int xr = (r16 & 7) << 4;
  const int cb0 = (g * 16) ^ xr, cb1 = (64 + g * 16) ^ xr;
  const int rdA = wm * 16384 + r16 * 128;
  const int rdB = 32768 + (wn >> 1) * 16384 + (wn & 1) * 8192 + r16 * 128;

  const char* A0g = Aby + (size_t)m0 * Ks;
  const char* A1g = Aby + (size_t)(m0 + 128) * Ks;
  const char* B0g = Bby + (size_t)n0 * Ks;
  const char* B1g = Bby + (size_t)(n0 + 128) * Ks;

  f32x4 acc[8][4] = {};
  bf16x8 a0[4][2], a1[4][2], bb01[2][2], bb23[2][2];

  auto read_a0bb01 = [&](const char* buf) {
#pragma unroll
    for (int n = 0; n < 2; ++n) bb01[n][0] = *(const bf16x8*)(buf + rdB + n * 2048 + cb0);
#pragma unroll
    for (int n = 0; n < 2; ++n) bb01[n][1] = *(const bf16x8*)(buf + rdB + n * 2048 + cb1);
#pragma unroll
    for (int m = 0; m < 4; ++m) a0[m][0] = *(const bf16x8*)(buf + rdA + m * 2048 + cb0);
#pragma unroll
    for (int m = 0; m < 4; ++m) a0[m][1] = *(const bf16x8*)(buf + rdA + m * 2048 + cb1);
  };

  // ---- prologue: tile0 {A0,A1,B0,B1} -> buf0; tile1 {B0,A0,A1} -> buf1 ----
  stage_half(A0g, Ks, lds + 0,     tid);
  stage_half(A1g, Ks, lds + 16384, tid);
  stage_half(B0g, Ks, lds + 32768, tid);
  stage_half(B1g, Ks, lds + 49152, tid);
  stage_half(B0g + 128, Ks, lds + 65536 + 32768, tid);
  stage_half(A0g + 128, Ks, lds + 65536 + 0,     tid);
  stage_half(A1g + 128, Ks, lds + 65536 + 16384, tid);
  VM6(); BAR();
  read_a0bb01(lds);  // tile 0

  for (int t = 0; t < NT; ++t) {
    const char* bufc = lds + (size_t)(t & 1) * 65536;
    char* bufn = lds + (size_t)((t + 1) & 1) * 65536;
    char* bufs = lds + (size_t)(t & 1) * 65536;
    // ---- P1: a0/bb01 ready; issue bb23 then a1; G1 ----
    LGKM(0);
#pragma unroll
    for (int n = 0; n < 2; ++n) bb23[n][0] = *(const bf16x8*)(bufc + rdB + (2 + n) * 2048 + cb0);
#pragma unroll
    for (int n = 0; n < 2; ++n) bb23[n][1] = *(const bf16x8*)(bufc + rdB + (2 + n) * 2048 + cb1);
#pragma unroll
    for (int m = 0; m < 4; ++m) a1[m][0] = *(const bf16x8*)(bufc + rdA + 8192 + m * 2048 + cb0);
#pragma unroll
    for (int m = 0; m < 4; ++m) a1[m][1] = *(const bf16x8*)(bufc + rdA + 8192 + m * 2048 + cb1);
    SCHED0();
    mfma_burst<0, 0, 0>(a0, bb01, acc);
    mfma_burst<0, 0, 1>(a0, bb01, acc);
    SCHED0(); BAR();
    // ---- P2: bb23 ready; stage B1(t+1); G2 ----
    LGKM(8);
    if (t + 1 < NT)
      stage_half(B1g + (size_t)(t + 1) * 128, Ks, bufn + 49152, tid);
    SCHED0();
    mfma_burst<0, 1, 0>(a0, bb23, acc);
    mfma_burst<0, 1, 1>(a0, bb23, acc);
    SCHED0(); BAR();
    // ---- P3: a1 ready; stage B0(t+2); G3 ----
    LGKM(0);
    if (t + 2 < NT)
      stage_half(B0g + (size_t)(t + 2) * 128, Ks, bufs + 32768, tid);
    SCHED0();
    mfma_burst<1, 0, 0>(a1, bb01, acc);
    mfma_burst<1, 0, 1>(a1, bb01, acc);
    SCHED0(); BAR();
    // ---- P4: counted vmcnt confirms tile t+1; stage A0,A1(t+2); G4 ----
    if (t < NT - 2) { VM2(); } else if (t == NT - 2) { VM0(); }
    if (t + 2 < NT) {
      stage_half(A0g + (size_t)(t + 2) * 128, Ks, bufs + 0,     tid);
      stage_half(A1g + (size_t)(t + 2) * 128, Ks, bufs + 16384, tid);
    }
    SCHED0();
    mfma_burst<1, 1, 0>(a1, bb23, acc);
    mfma_burst<1, 1, 1>(a1, bb23, acc);
    SCHED0(); BAR();
    if (t + 1 < NT) read_a0bb01(bufn);  // read-ahead for next tile
  }

  // ---- epilogue ----
  const int mrow = m0 + wm * 128 + g * 4;
  if constexpr (MODE == 0) {
    if (n0 < 3072) {
      // Fused RoPE, same-lane pairing: acc[i][2jp] holds dim d_e, acc[i][2jp+1]
      // holds d_e+128 (col = wn*64 + jp*32 + r16, bit4 always 0).
      const bool isQ = (n0 < 2048);
      bf16* Cb = isQ ? (Cq + n0) : (Ck + (n0 - 2048));
      const int ld = isQ ? 2048 : 1024;
#pragma unroll
      for (int i = 0; i < 8; ++i)
#pragma unroll
        for (int jp = 0; jp < 2; ++jp) {
          const int col = wn * 64 + jp * 32 + r16;
          const int de = (col & 15) | (((col >> 5) & 7) << 4);
#pragma unroll
          for (int e = 0; e < 4; ++e) {
            const int m = mrow + i * 16 + e;
            const float c  = cosb[(size_t)m * 256 + de];
            const float sn = sinb[(size_t)m * 256 + de];
            const float v0 = acc[i][jp * 2][e];
            const float v1 = acc[i][jp * 2 + 1][e];
            Cb[(size_t)m * ld + de]       = (bf16)(v0 * c - v1 * sn);
            Cb[(size_t)m * ld + de + 128] = (bf16)(v1 * c + v0 * sn);
          }
        }
    } else {
      const int ncol = n0 + wn * 64 + r16;
#pragma unroll
      for (int i = 0; i < 8; ++i)
#pragma unroll
        for (int j = 0; j < 4; ++j)
#pragma unroll
          for (int e = 0; e < 4; ++e) {
            const int m = mrow + i * 16 + e;
            const int n = ncol + j * 16;
            const int b2 = m >> 11, s = m & 2047;
            Cvt[((size_t)b2 * 1024 + (n - 3072)) * SEQ + s] = (bf16)acc[i][j][e];
          }
    }
  } else {
    const int ncol = n0 + wn * 64 + r16;
#pragma unroll
    for (int i = 0; i < 8; ++i)
#pragma unroll
      for (int j = 0; j < 4; ++j)
#pragma unroll
        for (int e = 0; e < 4; ++e) {
          const int m = mrow + i * 16 + e;
          const int n = ncol + j * 16;
          fo[(size_t)m * Nd + n] = acc[i][j][e] + resid[(size_t)m * Nd + n];
        }
  }
}

// ---------------- attention tile loads (K 32x256, V^T 256x32) ----------------
__device__ __forceinline__ void attn_load(const bf16* __restrict__ kgp, const bf16* __restrict__ vgp,
                                          int j0, int t, bf16x8* kr, bf16x8* vr) {
#pragma unroll
  for (int it = 0; it < 4; ++it) {
    const int flat = it * 2048 + t * 8;
    kr[it] = *(const bf16x8*)&kgp[(size_t)((flat >> 8) + j0) * NKV + (flat & 255)];
    vr[it] = *(const bf16x8*)&vgp[(size_t)(flat >> 5) * SEQ + j0 + (flat & 31)];
  }
}

// ---------------- Flash attention: QT=64 (4 waves x 16 rows), KT=32 --------
// r14 version (proven best): stride-40 LDS rows (80 B, 16B-aligned), paired
// heavy+light block mapping (b=0 ascending qt, b=1 descending) -> balanced
// ~36 tiles/CU under round-robin placement; register prefetch of next tile
// + 3 blocks/CU hides HBM latency.
__global__ __launch_bounds__(256) void attn_kernel(const bf16* __restrict__ q, const bf16* __restrict__ k,
                                                   const bf16* __restrict__ vt, bf16* __restrict__ ao) {
  __shared__ bf16 smem[21248];
  bf16* const qs  = smem;          // [64][264] (phase 1 only)
  bf16* const ksl = smem;          // [32][264]
  bf16* const vtl = smem + 8448;   // [256][40]
  bf16* const pl  = smem + 18688;  // [4][16][40]
  int qt = blockIdx.x;
  const int h = blockIdx.y, b = blockIdx.z;
  if (b) qt = 31 - qt;             // pair heavy+light across the grid
  const int kvh = h >> 1;
  const int t = threadIdx.x, lane = t & 63, w = t >> 6;
  const int r16 = lane & 15, g = lane >> 4;
  const int i_base = qt * 64;

  {
    const bf16* qg = q + ((size_t)(b * SEQ + i_base)) * NQ + h * 256;
#pragma unroll
    for (int it = 0; it < 8; ++it) {
      const int flat = it * 2048 + t * 8;
      const int row = flat >> 8, dd = flat & 255;
      *(bf16x8*)&qs[row * 264 + dd] = *(const bf16x8*)&qg[(size_t)row * NQ + dd];
    }
  }
  __syncthreads();
  bf16x8 aq[8];
#pragma unroll
  for (int c = 0; c < 8; ++c) aq[c] = *(const bf16x8*)&qs[(w * 16 + r16) * 264 + c * 32 + g * 8];

  f32x4 oacc[16] = {};
  float lrun[4] = {0.f, 0.f, 0.f, 0.f};
  int jb = i_base - 1023; if (jb < 0) jb = 0; jb &= ~31;
  const int je = i_base + 63;
  const bf16* kg = k + (size_t)b * SEQ * NKV + kvh * 256;
  const bf16* vg = vt + ((size_t)b * NKV + kvh * 256) * SEQ;

  bf16x8 kr[4], vr[4];
  attn_load(kg, vg, jb, t, kr, vr);

  for (int j0 = jb; j0 <= je; j0 += 32) {
    __syncthreads();
#pragma unroll
    for (int it = 0; it < 4; ++it) {
      const int flat = it * 2048 + t * 8;
      *(bf16x8*)&ksl[(flat >> 8) * 264 + (flat & 255)] = kr[it];
      *(bf16x8*)&vtl[(flat >> 5) * 40 + (flat & 31)] = vr[it];
    }
    __syncthreads();
    const int jn = (j0 + 32 <= je) ? (j0 + 32) : j0;
    attn_load(kg, vg, jn, t, kr, vr);

    f32x4 sc0 = {}, sc1 = {};
#pragma unroll
    for (int c = 0; c < 8; ++c) {
      const bf16x8 b0 = *(const bf16x8*)&ksl[r16 * 264 + c * 32 + g * 8];
      const bf16x8 b1 = *(const bf16x8*)&ksl[(16 + r16) * 264 + c * 32 + g * 8];
      sc0 = __builtin_amdgcn_mfma_f32_16x16x32_bf16(aq[c], b0, sc0, 0, 0, 0);
      sc1 = __builtin_amdgcn_mfma_f32_16x16x32_bf16(aq[c], b1, sc1, 0, 0, 0);
    }
    const bool full = (j0 + 31 <= i_base) && (i_base + 63 - j0 < 1024);
#pragma unroll
    for (int e = 0; e < 4; ++e) {
      const float t0 = __expf(sc0[e] * 0.0025f);
      const float t1 = __expf(sc1[e] * 0.0025f);
      float p0 = __expf(-100.0f / (t0 + 1.0f));
      float p1 = __expf(-100.0f / (t1 + 1.0f));
      if (!full) {
        const int irow = i_base + w * 16 + g * 4 + e;
        const int jg0 = j0 + r16, jg1 = j0 + 16 + r16;
        if (jg0 > irow || irow - jg0 >= 1024) p0 = 0.f;
        if (jg1 > irow || irow - jg1 >= 1024) p1 = 0.f;
      }
      const bf16 b0 = (bf16)p0, b1 = (bf16)p1;
      lrun[e] += (float)b0 + (float)b1;
      pl[w * 640 + (g * 4 + e) * 40 + r16] = b0;
      pl[w * 640 + (g * 4 + e) * 40 + 16 + r16] = b1;
    }
    // per-wave P buffer: same-wave LDS write->read dependency, no barrier needed
    const bf16x8 pa = *(const bf16x8*)&pl[w * 640 + r16 * 40 + g * 8];
#pragma unroll
    for (int nf = 0; nf < 16; ++nf) {
      const bf16x8 vb = *(const bf16x8*)&vtl[(nf * 16 + r16) * 40 + g * 8];
      oacc[nf] = __builtin_amdgcn_mfma_f32_16x16x32_bf16(pa, vb, oacc[nf], 0, 0, 0);
    }
  }
  float inv[4];
#pragma unroll
  for (int e = 0; e < 4; ++e) {
#pragma unroll
    for (int o = 1; o < 16; o <<= 1) lrun[e] += __shfl_xor(lrun[e], o, 64);
    inv[e] = 1.0f / lrun[e];
  }
  bf16* aor = ao + ((size_t)(b * SEQ + i_base + w * 16)) * NQ + h * 256;
#pragma unroll
  for (int nf = 0; nf < 16; ++nf)
#pragma unroll
    for (int e = 0; e < 4; ++e)
      aor[(size_t)(g * 4 + e) * NQ + nf * 16 + r16] = (bf16)(oacc[nf][e] * inv[e]);
}

extern "C" void kernel_launch(void* const* d_in, const int* in_sizes, int n_in,
                              void* d_out, int out_size, void* d_ws, size_t ws_size,
                              hipStream_t stream) {
  const float* hs   = (const float*)d_in[0];
  const float* cosb = (const float*)d_in[1];
  const float* sinb = (const float*)d_in[2];
  const float* rw   = (const float*)d_in[3];
  const float* Wq   = (const float*)d_in[4];
  const float* Wk   = (const float*)d_in[5];
  const float* Wv   = (const float*)d_in[6];
  const float* Wo   = (const float*)d_in[7];
  float* out = (float*)d_out;
  char* ws = (char*)d_ws;

  bf16* xb   = (bf16*)(ws);             // 4096x2304
  bf16* wqkv = (bf16*)(ws + 18874368);  // [4096][2304]: Wq(2048) | Wk(1024) | Wv(1024)
  bf16* wkb  = wqkv + (size_t)2048 * 2304;
  bf16* wvb  = wqkv + (size_t)3072 * 2304;
  bf16* wob  = (bf16*)(ws + 37748736);  // 2304x2048
  bf16* qg   = (bf16*)(ws + 47185920);  // 4096x2048
  bf16* kg   = (bf16*)(ws + 63963136);  // 4096x1024
  bf16* vtg  = (bf16*)(ws + 72351744);  // [2][1024][2048]
  bf16* ag   = (bf16*)(ws + 80740352);  // 4096x2048

  rmsnorm_kernel<<<4096, 256, 0, stream>>>(hs, rw, xb);
  cvt4_kernel<<<(NW0 + 2 * NW1 + NW3) / 4 / 256, 256, 0, stream>>>(Wq, Wk, Wv, Wo, wqkv, wkb, wvb, wob);
  // QKV: M=4096, N=4096, K=2304 (NT=36), grid 16x16=256, fused RoPE epilogue
  gemm8p<36, 16, 0><<<256, 512, 0, stream>>>(xb, wqkv, qg, kg, vtg, nullptr, nullptr, 4096, cosb, sinb);
  attn_kernel<<<dim3(32, 8, 2), 256, 0, stream>>>(qg, kg, vtg, ag);
  // O-proj: M=4096, N=2304, K=2048 (NT=32), grid 16x9=144, direct f32+resid
  gemm8p<32, 9, 1><<<144, 512, 0, stream>>>(ag, wob, nullptr, nullptr, nullptr, out, hs, 2304, nullptr, nullptr);
}